// Round 3
// baseline (206.477 us; speedup 1.0000x reference)
//
#include <hip/hip_runtime.h>
#include <hip/hip_bf16.h>
#include <stdint.h>

// B=8, N=1024, D=768, H=12, hd=64
// cvt(x,Wqkv,Wproj -> bf16 ws) -> MFMA gemm qkv -> MFMA flash attention -> MFMA gemm proj + bias

typedef unsigned short u16;
typedef __attribute__((ext_vector_type(8))) short short8;
typedef __attribute__((ext_vector_type(4))) float f32x4;

#define MFMA16(a, b, c) __builtin_amdgcn_mfma_f32_16x16x32_bf16((a), (b), (c), 0, 0, 0)

static __device__ __forceinline__ u16 f2bf(float f) {
    __hip_bfloat16 h = __float2bfloat16(f);
    return *(u16*)&h;
}
// async global->LDS, 16B per lane; LDS dest must be wave-uniform base + lane*16
static __device__ __forceinline__ void gld16(const u16* g, u16* l) {
  __builtin_amdgcn_global_load_lds(
      (const __attribute__((address_space(1))) void*)g,
      (__attribute__((address_space(3))) void*)l, 16, 0, 0);
}

// ---------------- fp32 -> bf16 conversion of the three input tensors
__global__ __launch_bounds__(256) void cvt_bf16(
    const float* __restrict__ s0, u16* __restrict__ d0, int n0,
    const float* __restrict__ s1, u16* __restrict__ d1, int n1,
    const float* __restrict__ s2, u16* __restrict__ d2, int n2) {
  int i = (blockIdx.x * 256 + threadIdx.x) * 4;
  const float* s; u16* d;
  if (i < n0) { s = s0 + i; d = d0 + i; }
  else if ((i -= n0) < n1) { s = s1 + i; d = d1 + i; }
  else if ((i -= n1) < n2) { s = s2 + i; d = d2 + i; }
  else return;
  float4 v = *(const float4*)s;
  ushort4 o;
  o.x = f2bf(v.x); o.y = f2bf(v.y); o.z = f2bf(v.z); o.w = f2bf(v.w);
  *(ushort4*)d = o;
}

// ---------------- MFMA GEMM: C[M][LDC] = A[M][K](bf16) * B[N][K](bf16)^T
// m97 structure, BK=64 (round 3): halves the per-K-step vmcnt(0)+barrier
// drain count (24 -> 12 for K=768) — the ~20% structural stall of the
// 2-barrier loop. LDS 32 KB caps occupancy at 5 blocks/CU; grids supply
// 4.5 (qkv) / 3 (proj), so occupancy is unchanged vs BK=32.
template<int K, int BN, int LDC, bool BF16OUT>
__global__ __launch_bounds__(256) void gemm_bt(
    const u16* __restrict__ A,
    const u16* __restrict__ B,
    void* __restrict__ Cout,
    const float* __restrict__ bias) {
  constexpr int NT = BN / 32;          // n-tiles per wave
  __shared__ u16 As[128 * 64];
  __shared__ u16 Bs[BN * 64];
  const int tid = threadIdx.x;
  const int w = tid >> 6, l = tid & 63;
  const int lane16 = l & 15, quad = l >> 4;
  const int i0 = blockIdx.y * 128, j0 = blockIdx.x * BN;
  const int mh = (w & 1) * 64;
  const int nh = (w >> 1) * (BN / 2);

  f32x4 acc[4][NT];
  #pragma unroll
  for (int mt = 0; mt < 4; mt++)
    #pragma unroll
    for (int nt = 0; nt < NT; nt++) acc[mt][nt] = (f32x4){0.f, 0.f, 0.f, 0.f};

  for (int kt = 0; kt < K / 64; kt++) {
    const int k0 = kt * 64;
    __syncthreads();
    #pragma unroll
    for (int s = 0; s < 4; s++) {            // A: 128x64 bf16 -> 4 gld16/thread
      int idx = tid + s * 256;
      int row = idx >> 3, c8 = (idx & 7) * 8;
      gld16(&A[(size_t)(i0 + row) * K + k0 + c8], &As[idx * 8]);
    }
    #pragma unroll
    for (int s = 0; s < BN / 32; s++) {      // B: BNx64 bf16
      int idx = tid + s * 256;
      int row = idx >> 3, c8 = (idx & 7) * 8;
      gld16(&B[(size_t)(j0 + row) * K + k0 + c8], &Bs[idx * 8]);
    }
    __syncthreads();

    #pragma unroll
    for (int ks = 0; ks < 2; ks++) {
      short8 af[4], bf[NT];
      #pragma unroll
      for (int mt = 0; mt < 4; mt++)
        af[mt] = *(const short8*)&As[(mh + mt * 16 + lane16) * 64 + ks * 32 + quad * 8];
      #pragma unroll
      for (int nt = 0; nt < NT; nt++)
        bf[nt] = *(const short8*)&Bs[(nh + nt * 16 + lane16) * 64 + ks * 32 + quad * 8];
      #pragma unroll
      for (int mt = 0; mt < 4; mt++)
        #pragma unroll
        for (int nt = 0; nt < NT; nt++)
          acc[mt][nt] = MFMA16(af[mt], bf[nt], acc[mt][nt]);
    }
  }

  #pragma unroll
  for (int mt = 0; mt < 4; mt++) {
    #pragma unroll
    for (int nt = 0; nt < NT; nt++) {
      int col = j0 + nh + nt * 16 + lane16;
      #pragma unroll
      for (int r = 0; r < 4; r++) {
        int row = i0 + mh + mt * 16 + quad * 4 + r;
        if (BF16OUT) {
          ((u16*)Cout)[(size_t)row * LDC + col] = f2bf(acc[mt][nt][r]);
        } else {
          ((float*)Cout)[(size_t)row * LDC + col] = acc[mt][nt][r] + bias[col];
        }
      }
    }
  }
}

// ---------------- Attention: MFMA flash, transposed-S, fixed-max softmax.
// r6 structure + T14 async-STAGE + setprio + f32x4 lsum (round 2, verified).
// Round 3: mask bias hoisted to a one-time mkb_all[1024] LDS table in the
// prologue — removes the per-chunk mask global-load + LDS-write from the
// staging path (and the mqs array). LDS 40 KB, still 3 blocks/CU (= grid).
// XCD swizzle: idx = rb*96 + bh so all 8 row-blocks of one (b,h) share an XCD L2.
// Block = 4 waves, 128 q-rows, grid 768.
__global__ __launch_bounds__(256, 3) void attn_mfma(
    const u16* __restrict__ qkv,   // bf16 bits, [B*N][2304]; q +0, k +768, v +1536 (+h*64)
    const int* __restrict__ mask,
    u16* __restrict__ ctx) {
  __shared__ u16 Ks[64][72];      // [key][dim]
  __shared__ u16 Vt[64][72];      // [dim][key]
  __shared__ u16 Ps[4][32][72];   // per-wave P [qrow_local][key]
  __shared__ float mkb_all[1024]; // 0 or -1e38 additive key-mask bias, whole seq

  const int tid = threadIdx.x;
  const int w = tid >> 6, l = tid & 63;
  const int lane16 = l & 15, quad = l >> 4;
  const int idx = blockIdx.x;
  const int bh = idx % 96;        // 96 % 8 == 0 -> same bh => same XCD
  const int rb = idx / 96;
  const int b = bh / 12, h = bh % 12;
  const int n0 = rb * 128;
  const int baseRow = b * 1024;

  // staging thread mapping
  const int key_s = tid >> 2, ds_s = (tid & 3) * 16;      // K: 1 key, 32 dims
  const int kA_s = (tid & 31) * 2, dg_s = tid >> 5;       // V: 2 keys, 8 dims

  // whole-sequence mask bias table (written once; first compute barrier covers it)
  {
    int4 mv = *(const int4*)&mask[baseRow + tid * 4];
    f32x4 mf;
    mf[0] = mv.x ? 0.f : -1e38f;
    mf[1] = mv.y ? 0.f : -1e38f;
    mf[2] = mv.z ? 0.f : -1e38f;
    mf[3] = mv.w ? 0.f : -1e38f;
    *(f32x4*)&mkb_all[tid * 4] = mf;
  }

  // Q fragments (used as MFMA B operand): n=lane16 (local qrow), k=quad*8+j
  short8 qfrag[2][2];
  #pragma unroll
  for (int qt = 0; qt < 2; qt++) {
    const u16* qp = qkv + (size_t)(baseRow + n0 + w*32 + qt*16 + lane16) * 2304 + h*64;
    #pragma unroll
    for (int ks = 0; ks < 2; ks++)
      qfrag[qt][ks] = *(const short8*)(qp + ks*32 + quad*8);
  }

  f32x4 oacc[2][4];     // [qt][nt(dim)]; C-layout row=quad*4+r=qrow, col=lane16=dim
  #pragma unroll
  for (int qt = 0; qt < 2; qt++)
    #pragma unroll
    for (int nt = 0; nt < 4; nt++) oacc[qt][nt] = (f32x4){0.f, 0.f, 0.f, 0.f};
  f32x4 lsum4[2] = {(f32x4){0.f,0.f,0.f,0.f}, (f32x4){0.f,0.f,0.f,0.f}};

  // exp(s/8 - 16) == exp2(s*K1 + K0); fixed max >> max score (~8 sigma), overflow-free.
  const float K1 = 0.18033688011112043f;   // log2(e)/8
  const float K0 = -23.083120654223415f;   // -16*log2(e)

  // ---- T14 prologue: issue chunk-0 K/V loads into registers
  uint4 kr0, kr1, vr0, vr1;
  {
    const u16* kp = qkv + (size_t)(baseRow + key_s) * 2304 + 768 + h*64 + ds_s;
    kr0 = *(const uint4*)kp;
    kr1 = *(const uint4*)(kp + 8);
    const u16* vp = qkv + (size_t)(baseRow + kA_s) * 2304 + 1536 + h*64 + dg_s*8;
    vr0 = *(const uint4*)vp;
    vr1 = *(const uint4*)(vp + 2304);
  }

  for (int c = 0; c < 16; c++) {
    if (c) __syncthreads();   // prior chunk's LDS reads complete before overwrite

    // ---- write staged registers (chunk c) into LDS
    *(uint4*)&Ks[key_s][ds_s]     = kr0;
    *(uint4*)&Ks[key_s][ds_s + 8] = kr1;
    {
      const u16* va = (const u16*)&vr0;
      const u16* vb = (const u16*)&vr1;
      #pragma unroll
      for (int j = 0; j < 8; j++)
        *(unsigned int*)&Vt[dg_s*8 + j][kA_s] =
            (unsigned int)va[j] | ((unsigned int)vb[j] << 16);
    }

    // ---- issue chunk c+1's global loads (registers only; latency hides
    //      under this chunk's MFMA + softmax)
    if (c + 1 < 16) {
      const u16* kp = qkv + (size_t)(baseRow + (c+1)*64 + key_s) * 2304 + 768 + h*64 + ds_s;
      kr0 = *(const uint4*)kp;
      kr1 = *(const uint4*)(kp + 8);
      const u16* vp = qkv + (size_t)(baseRow + (c+1)*64 + kA_s) * 2304 + 1536 + h*64 + dg_s*8;
      vr0 = *(const uint4*)vp;
      vr1 = *(const uint4*)(vp + 2304);
    }
    __syncthreads();          // chunk c visible to all waves

    // S^T = K * Q^T : A=K (m=key), B=Q (n=qrow). C-layout: row=key, col=qrow.
    f32x4 sacc[4][2];
    #pragma unroll
    for (int kt = 0; kt < 4; kt++)
      #pragma unroll
      for (int qt = 0; qt < 2; qt++) sacc[kt][qt] = (f32x4){0.f, 0.f, 0.f, 0.f};
    #pragma unroll
    for (int ks = 0; ks < 2; ks++) {
      short8 kf[4];
      #pragma unroll
      for (int kt = 0; kt < 4; kt++)
        kf[kt] = *(const short8*)&Ks[kt*16 + lane16][ks*32 + quad*8];
      __builtin_amdgcn_s_setprio(1);
      #pragma unroll
      for (int kt = 0; kt < 4; kt++)
        #pragma unroll
        for (int qt = 0; qt < 2; qt++)
          sacc[kt][qt] = MFMA16(kf[kt], qfrag[qt][ks], sacc[kt][qt]);
      __builtin_amdgcn_s_setprio(0);
    }

    // softmax: row=quad*4+r = key-local, col=lane16 = qrow-local. Vectorized P write.
    #pragma unroll
    for (int kt = 0; kt < 4; kt++) {
      f32x4 mk4 = *(const f32x4*)&mkb_all[c*64 + kt*16 + quad*4];   // contiguous keys
      #pragma unroll
      for (int qt = 0; qt < 2; qt++) {
        u16 pk[4];
        #pragma unroll
        for (int r = 0; r < 4; r++) {
          float e = __builtin_amdgcn_exp2f(fmaf(sacc[kt][qt][r], K1, K0) + mk4[r]);
          lsum4[qt][r] += e;
          pk[r] = f2bf(e);
        }
        uint2 pv;
        pv.x = (unsigned int)pk[0] | ((unsigned int)pk[1] << 16);
        pv.y = (unsigned int)pk[2] | ((unsigned int)pk[3] << 16);
        *(uint2*)&Ps[w][qt*16 + lane16][kt*16 + quad*4] = pv;
      }
    }

    // O += P * V : A=P (m=qrow, k=key) own-wave LDS; B=V^T (n=dim, k=key) from Vt.
    #pragma unroll
    for (int kc = 0; kc < 2; kc++) {
      short8 pf[2], vf[4];
      #pragma unroll
      for (int qt = 0; qt < 2; qt++)
        pf[qt] = *(const short8*)&Ps[w][qt*16 + lane16][kc*32 + quad*8];
      #pragma unroll
      for (int nt = 0; nt < 4; nt++)
        vf[nt] = *(const short8*)&Vt[nt*16 + lane16][kc*32 + quad*8];
      __builtin_amdgcn_s_setprio(1);
      #pragma unroll
      for (int qt = 0; qt < 2; qt++)
        #pragma unroll
        for (int nt = 0; nt < 4; nt++)
          oacc[qt][nt] = MFMA16(pf[qt], vf[nt], oacc[qt][nt]);
      __builtin_amdgcn_s_setprio(0);
    }
  }

  // lsum: reduce across quads, then redistribute to the C-layout row owner.
  float linv[2][4];
  #pragma unroll
  for (int qt = 0; qt < 2; qt++) {
    float s = lsum4[qt][0] + lsum4[qt][1] + lsum4[qt][2] + lsum4[qt][3];
    s += __shfl_xor(s, 16);
    s += __shfl_xor(s, 32);   // every lane: total for qrow = its lane16 (tile qt)
    #pragma unroll
    for (int r = 0; r < 4; r++)
      linv[qt][r] = 1.0f / __shfl(s, quad*4 + r);
  }
  // store; masked query rows get exactly their own V row (bit-exact copy)
  #pragma unroll
  for (int qt = 0; qt < 2; qt++) {
    #pragma unroll
    for (int r = 0; r < 4; r++) {
      int rl = w*32 + qt*16 + quad*4 + r;
      int rg = n0 + rl;
      int mq = (mkb_all[n0 + rl] == 0.f);
      #pragma unroll
      for (int nt = 0; nt < 4; nt++) {
        u16 outv;
        if (mq) {
          outv = f2bf(oacc[qt][nt][r] * linv[qt][r]);
        } else {
          outv = qkv[(size_t)(baseRow + rg) * 2304 + 1536 + h*64 + nt*16 + lane16];
        }
        ctx[(size_t)(baseRow + rg) * 768 + h*64 + nt*16 + lane16] = outv;
      }
    }
  }
}

extern "C" void kernel_launch(void* const* d_in, const int* in_sizes, int n_in,
                              void* d_out, int out_size, void* d_ws, size_t ws_size,
                              hipStream_t stream) {
  const float* x     = (const float*)d_in[0];
  const int*   mask  = (const int*)d_in[1];
  const float* Wqkv  = (const float*)d_in[2];
  const float* Wproj = (const float*)d_in[3];
  const float* bproj = (const float*)d_in[4];
  float* out = (float*)d_out;

  const int NX = 8192 * 768;
  const int NQ = 2304 * 768;
  const int NP = 768 * 768;

  char* wsb = (char*)d_ws;
  u16* qkv    = (u16*)wsb;                                  // 37.75 MB
  u16* ctx    = (u16*)(wsb + (size_t)8192 * 2304 * 2);      // 12.58 MB
  u16* xb     = (u16*)(wsb + (size_t)8192 * 2304 * 2 + (size_t)8192 * 768 * 2);
  u16* wqkvb  = xb + NX;
  u16* wprojb = wqkvb + NQ;

  int cvt_blocks = ((NX + NQ + NP) / 4 + 255) / 256;
  cvt_bf16<<<dim3(cvt_blocks), 256, 0, stream>>>(x, xb, NX, Wqkv, wqkvb, NQ, Wproj, wprojb, NP);

  gemm_bt<768, 128, 2304, true><<<dim3(18, 64), 256, 0, stream>>>(xb, wqkvb, qkv, nullptr);
  attn_mfma<<<dim3(768), 256, 0, stream>>>(qkv, mask, ctx);
  gemm_bt<768, 64, 768, false><<<dim3(12, 64), 256, 0, stream>>>(ctx, wprojb, out, bproj);
}

// Round 4
// 202.433 us; speedup vs baseline: 1.0200x; 1.0200x over previous
//
#include <hip/hip_runtime.h>
#include <hip/hip_bf16.h>
#include <stdint.h>

// B=8, N=1024, D=768, H=12, hd=64
// cvt(x,Wqkv,Wproj -> bf16 ws) -> MFMA gemm qkv -> MFMA flash attention -> MFMA gemm proj + bias

typedef unsigned short u16;
typedef __attribute__((ext_vector_type(8))) short short8;
typedef __attribute__((ext_vector_type(4))) float f32x4;

#define MFMA16(a, b, c) __builtin_amdgcn_mfma_f32_16x16x32_bf16((a), (b), (c), 0, 0, 0)

static __device__ __forceinline__ u16 f2bf(float f) {
    __hip_bfloat16 h = __float2bfloat16(f);
    return *(u16*)&h;
}
// async global->LDS, 16B per lane; LDS dest must be wave-uniform base + lane*16
static __device__ __forceinline__ void gld16(const u16* g, u16* l) {
  __builtin_amdgcn_global_load_lds(
      (const __attribute__((address_space(1))) void*)g,
      (__attribute__((address_space(3))) void*)l, 16, 0, 0);
}

// ---------------- fp32 -> bf16 conversion of the three input tensors
__global__ __launch_bounds__(256) void cvt_bf16(
    const float* __restrict__ s0, u16* __restrict__ d0, int n0,
    const float* __restrict__ s1, u16* __restrict__ d1, int n1,
    const float* __restrict__ s2, u16* __restrict__ d2, int n2) {
  int i = (blockIdx.x * 256 + threadIdx.x) * 4;
  const float* s; u16* d;
  if (i < n0) { s = s0 + i; d = d0 + i; }
  else if ((i -= n0) < n1) { s = s1 + i; d = d1 + i; }
  else if ((i -= n1) < n2) { s = s2 + i; d = d2 + i; }
  else return;
  float4 v = *(const float4*)s;
  ushort4 o;
  o.x = f2bf(v.x); o.y = f2bf(v.y); o.z = f2bf(v.z); o.w = f2bf(v.w);
  *(ushort4*)d = o;
}

// ---------------- MFMA GEMM: C[M][LDC] = A[M][K](bf16) * B[N][K](bf16)^T
// Round 4: BK=32 (BK=64 regressed: longer drains + 128B-stride 16-way LDS
// conflicts) + T3-minimum double-buffer: stage(t+1) issued BEFORE
// ds_read+MFMA of t, ONE vmcnt(0)+barrier per K-step (was 2). Loads for t+1
// fly during t's MFMA; drain at the barrier is then cheap. Named buffers,
// x2-unrolled loop (no runtime LDS index -> no scratch). LDS 32KB: occupancy
// cap 5 blocks/CU vs grid 4.5 (qkv) / 3 (proj) -> unchanged.
template<int K, int BN, int LDC, bool BF16OUT>
__global__ __launch_bounds__(256) void gemm_bt(
    const u16* __restrict__ A,
    const u16* __restrict__ B,
    void* __restrict__ Cout,
    const float* __restrict__ bias) {
  constexpr int NT = BN / 32;          // n-tiles per wave
  __shared__ u16 As0[128 * 32];
  __shared__ u16 Bs0[BN * 32];
  __shared__ u16 As1[128 * 32];
  __shared__ u16 Bs1[BN * 32];
  const int tid = threadIdx.x;
  const int w = tid >> 6, l = tid & 63;
  const int lane16 = l & 15, quad = l >> 4;
  const int i0 = blockIdx.y * 128, j0 = blockIdx.x * BN;
  const int mh = (w & 1) * 64;
  const int nh = (w >> 1) * (BN / 2);

  f32x4 acc[4][NT];
  #pragma unroll
  for (int mt = 0; mt < 4; mt++)
    #pragma unroll
    for (int nt = 0; nt < NT; nt++) acc[mt][nt] = (f32x4){0.f, 0.f, 0.f, 0.f};

  auto stage = [&](u16* Ad, u16* Bd, int k0) {
    #pragma unroll
    for (int s = 0; s < 2; s++) {            // A: 128x32 bf16 -> 2 gld16/thread
      int idx = tid + s * 256;
      int row = idx >> 2, c8 = (idx & 3) * 8;
      gld16(&A[(size_t)(i0 + row) * K + k0 + c8], &Ad[idx * 8]);
    }
    #pragma unroll
    for (int s = 0; s < BN / 64; s++) {      // B: BNx32 bf16
      int idx = tid + s * 256;
      int row = idx >> 2, c8 = (idx & 3) * 8;
      gld16(&B[(size_t)(j0 + row) * K + k0 + c8], &Bd[idx * 8]);
    }
  };
  auto compute = [&](const u16* Asb, const u16* Bsb) {
    short8 af[4], bf[NT];
    #pragma unroll
    for (int mt = 0; mt < 4; mt++)
      af[mt] = *(const short8*)&Asb[(mh + mt * 16 + lane16) * 32 + quad * 8];
    #pragma unroll
    for (int nt = 0; nt < NT; nt++)
      bf[nt] = *(const short8*)&Bsb[(nh + nt * 16 + lane16) * 32 + quad * 8];
    #pragma unroll
    for (int mt = 0; mt < 4; mt++)
      #pragma unroll
      for (int nt = 0; nt < NT; nt++)
        acc[mt][nt] = MFMA16(af[mt], bf[nt], acc[mt][nt]);
  };

  stage(As0, Bs0, 0);
  __syncthreads();                     // prologue: buf0 ready
  for (int kt2 = 0; kt2 < K / 64; kt2++) {
    const int k0 = kt2 * 64;
    stage(As1, Bs1, k0 + 32);          // issue next BEFORE compute
    compute(As0, Bs0);
    __syncthreads();                   // buf1 ready; buf0 reads done
    if (k0 + 64 < K) stage(As0, Bs0, k0 + 64);
    compute(As1, Bs1);
    __syncthreads();                   // buf0 ready; buf1 reads done
  }

  #pragma unroll
  for (int mt = 0; mt < 4; mt++) {
    #pragma unroll
    for (int nt = 0; nt < NT; nt++) {
      int col = j0 + nh + nt * 16 + lane16;
      #pragma unroll
      for (int r = 0; r < 4; r++) {
        int row = i0 + mh + mt * 16 + quad * 4 + r;
        if (BF16OUT) {
          ((u16*)Cout)[(size_t)row * LDC + col] = f2bf(acc[mt][nt][r]);
        } else {
          ((float*)Cout)[(size_t)row * LDC + col] = acc[mt][nt][r] + bias[col];
        }
      }
    }
  }
}

// ---------------- Attention: MFMA flash, transposed-S, fixed-max softmax.
// r6 structure + T14 async-STAGE + setprio + f32x4 lsum (round 2, verified)
// + mkb_all one-time mask table (round 3). LDS 40 KB, 3 blocks/CU (= grid).
// XCD swizzle: idx = rb*96 + bh so all 8 row-blocks of one (b,h) share an XCD L2.
// Block = 4 waves, 128 q-rows, grid 768.
__global__ __launch_bounds__(256, 3) void attn_mfma(
    const u16* __restrict__ qkv,   // bf16 bits, [B*N][2304]; q +0, k +768, v +1536 (+h*64)
    const int* __restrict__ mask,
    u16* __restrict__ ctx) {
  __shared__ u16 Ks[64][72];      // [key][dim]
  __shared__ u16 Vt[64][72];      // [dim][key]
  __shared__ u16 Ps[4][32][72];   // per-wave P [qrow_local][key]
  __shared__ float mkb_all[1024]; // 0 or -1e38 additive key-mask bias, whole seq

  const int tid = threadIdx.x;
  const int w = tid >> 6, l = tid & 63;
  const int lane16 = l & 15, quad = l >> 4;
  const int idx = blockIdx.x;
  const int bh = idx % 96;        // 96 % 8 == 0 -> same bh => same XCD
  const int rb = idx / 96;
  const int b = bh / 12, h = bh % 12;
  const int n0 = rb * 128;
  const int baseRow = b * 1024;

  // staging thread mapping
  const int key_s = tid >> 2, ds_s = (tid & 3) * 16;      // K: 1 key, 32 dims
  const int kA_s = (tid & 31) * 2, dg_s = tid >> 5;       // V: 2 keys, 8 dims

  // whole-sequence mask bias table (written once; first compute barrier covers it)
  {
    int4 mv = *(const int4*)&mask[baseRow + tid * 4];
    f32x4 mf;
    mf[0] = mv.x ? 0.f : -1e38f;
    mf[1] = mv.y ? 0.f : -1e38f;
    mf[2] = mv.z ? 0.f : -1e38f;
    mf[3] = mv.w ? 0.f : -1e38f;
    *(f32x4*)&mkb_all[tid * 4] = mf;
  }

  // Q fragments (used as MFMA B operand): n=lane16 (local qrow), k=quad*8+j
  short8 qfrag[2][2];
  #pragma unroll
  for (int qt = 0; qt < 2; qt++) {
    const u16* qp = qkv + (size_t)(baseRow + n0 + w*32 + qt*16 + lane16) * 2304 + h*64;
    #pragma unroll
    for (int ks = 0; ks < 2; ks++)
      qfrag[qt][ks] = *(const short8*)(qp + ks*32 + quad*8);
  }

  f32x4 oacc[2][4];     // [qt][nt(dim)]; C-layout row=quad*4+r=qrow, col=lane16=dim
  #pragma unroll
  for (int qt = 0; qt < 2; qt++)
    #pragma unroll
    for (int nt = 0; nt < 4; nt++) oacc[qt][nt] = (f32x4){0.f, 0.f, 0.f, 0.f};
  f32x4 lsum4[2] = {(f32x4){0.f,0.f,0.f,0.f}, (f32x4){0.f,0.f,0.f,0.f}};

  // exp(s/8 - 16) == exp2(s*K1 + K0); fixed max >> max score (~8 sigma), overflow-free.
  const float K1 = 0.18033688011112043f;   // log2(e)/8
  const float K0 = -23.083120654223415f;   // -16*log2(e)

  // ---- T14 prologue: issue chunk-0 K/V loads into registers
  uint4 kr0, kr1, vr0, vr1;
  {
    const u16* kp = qkv + (size_t)(baseRow + key_s) * 2304 + 768 + h*64 + ds_s;
    kr0 = *(const uint4*)kp;
    kr1 = *(const uint4*)(kp + 8);
    const u16* vp = qkv + (size_t)(baseRow + kA_s) * 2304 + 1536 + h*64 + dg_s*8;
    vr0 = *(const uint4*)vp;
    vr1 = *(const uint4*)(vp + 2304);
  }

  for (int c = 0; c < 16; c++) {
    if (c) __syncthreads();   // prior chunk's LDS reads complete before overwrite

    // ---- write staged registers (chunk c) into LDS
    *(uint4*)&Ks[key_s][ds_s]     = kr0;
    *(uint4*)&Ks[key_s][ds_s + 8] = kr1;
    {
      const u16* va = (const u16*)&vr0;
      const u16* vb = (const u16*)&vr1;
      #pragma unroll
      for (int j = 0; j < 8; j++)
        *(unsigned int*)&Vt[dg_s*8 + j][kA_s] =
            (unsigned int)va[j] | ((unsigned int)vb[j] << 16);
    }

    // ---- issue chunk c+1's global loads (registers only; latency hides
    //      under this chunk's MFMA + softmax)
    if (c + 1 < 16) {
      const u16* kp = qkv + (size_t)(baseRow + (c+1)*64 + key_s) * 2304 + 768 + h*64 + ds_s;
      kr0 = *(const uint4*)kp;
      kr1 = *(const uint4*)(kp + 8);
      const u16* vp = qkv + (size_t)(baseRow + (c+1)*64 + kA_s) * 2304 + 1536 + h*64 + dg_s*8;
      vr0 = *(const uint4*)vp;
      vr1 = *(const uint4*)(vp + 2304);
    }
    __syncthreads();          // chunk c visible to all waves

    // S^T = K * Q^T : A=K (m=key), B=Q (n=qrow). C-layout: row=key, col=qrow.
    f32x4 sacc[4][2];
    #pragma unroll
    for (int kt = 0; kt < 4; kt++)
      #pragma unroll
      for (int qt = 0; qt < 2; qt++) sacc[kt][qt] = (f32x4){0.f, 0.f, 0.f, 0.f};
    #pragma unroll
    for (int ks = 0; ks < 2; ks++) {
      short8 kf[4];
      #pragma unroll
      for (int kt = 0; kt < 4; kt++)
        kf[kt] = *(const short8*)&Ks[kt*16 + lane16][ks*32 + quad*8];
      __builtin_amdgcn_s_setprio(1);
      #pragma unroll
      for (int kt = 0; kt < 4; kt++)
        #pragma unroll
        for (int qt = 0; qt < 2; qt++)
          sacc[kt][qt] = MFMA16(kf[kt], qfrag[qt][ks], sacc[kt][qt]);
      __builtin_amdgcn_s_setprio(0);
    }

    // softmax: row=quad*4+r = key-local, col=lane16 = qrow-local. Vectorized P write.
    #pragma unroll
    for (int kt = 0; kt < 4; kt++) {
      f32x4 mk4 = *(const f32x4*)&mkb_all[c*64 + kt*16 + quad*4];   // contiguous keys
      #pragma unroll
      for (int qt = 0; qt < 2; qt++) {
        u16 pk[4];
        #pragma unroll
        for (int r = 0; r < 4; r++) {
          float e = __builtin_amdgcn_exp2f(fmaf(sacc[kt][qt][r], K1, K0) + mk4[r]);
          lsum4[qt][r] += e;
          pk[r] = f2bf(e);
        }
        uint2 pv;
        pv.x = (unsigned int)pk[0] | ((unsigned int)pk[1] << 16);
        pv.y = (unsigned int)pk[2] | ((unsigned int)pk[3] << 16);
        *(uint2*)&Ps[w][qt*16 + lane16][kt*16 + quad*4] = pv;
      }
    }

    // O += P * V : A=P (m=qrow, k=key) own-wave LDS; B=V^T (n=dim, k=key) from Vt.
    #pragma unroll
    for (int kc = 0; kc < 2; kc++) {
      short8 pf[2], vf[4];
      #pragma unroll
      for (int qt = 0; qt < 2; qt++)
        pf[qt] = *(const short8*)&Ps[w][qt*16 + lane16][kc*32 + quad*8];
      #pragma unroll
      for (int nt = 0; nt < 4; nt++)
        vf[nt] = *(const short8*)&Vt[nt*16 + lane16][kc*32 + quad*8];
      __builtin_amdgcn_s_setprio(1);
      #pragma unroll
      for (int qt = 0; qt < 2; qt++)
        #pragma unroll
        for (int nt = 0; nt < 4; nt++)
          oacc[qt][nt] = MFMA16(pf[qt], vf[nt], oacc[qt][nt]);
      __builtin_amdgcn_s_setprio(0);
    }
  }

  // lsum: reduce across quads, then redistribute to the C-layout row owner.
  float linv[2][4];
  #pragma unroll
  for (int qt = 0; qt < 2; qt++) {
    float s = lsum4[qt][0] + lsum4[qt][1] + lsum4[qt][2] + lsum4[qt][3];
    s += __shfl_xor(s, 16);
    s += __shfl_xor(s, 32);   // every lane: total for qrow = its lane16 (tile qt)
    #pragma unroll
    for (int r = 0; r < 4; r++)
      linv[qt][r] = 1.0f / __shfl(s, quad*4 + r);
  }
  // store; masked query rows get exactly their own V row (bit-exact copy)
  #pragma unroll
  for (int qt = 0; qt < 2; qt++) {
    #pragma unroll
    for (int r = 0; r < 4; r++) {
      int rl = w*32 + qt*16 + quad*4 + r;
      int rg = n0 + rl;
      int mq = (mkb_all[n0 + rl] == 0.f);
      #pragma unroll
      for (int nt = 0; nt < 4; nt++) {
        u16 outv;
        if (mq) {
          outv = f2bf(oacc[qt][nt][r] * linv[qt][r]);
        } else {
          outv = qkv[(size_t)(baseRow + rg) * 2304 + 1536 + h*64 + nt*16 + lane16];
        }
        ctx[(size_t)(baseRow + rg) * 768 + h*64 + nt*16 + lane16] = outv;
      }
    }
  }
}

extern "C" void kernel_launch(void* const* d_in, const int* in_sizes, int n_in,
                              void* d_out, int out_size, void* d_ws, size_t ws_size,
                              hipStream_t stream) {
  const float* x     = (const float*)d_in[0];
  const int*   mask  = (const int*)d_in[1];
  const float* Wqkv  = (const float*)d_in[2];
  const float* Wproj = (const float*)d_in[3];
  const float* bproj = (const float*)d_in[4];
  float* out = (float*)d_out;

  const int NX = 8192 * 768;
  const int NQ = 2304 * 768;
  const int NP = 768 * 768;

  char* wsb = (char*)d_ws;
  u16* qkv    = (u16*)wsb;                                  // 37.75 MB
  u16* ctx    = (u16*)(wsb + (size_t)8192 * 2304 * 2);      // 12.58 MB
  u16* xb     = (u16*)(wsb + (size_t)8192 * 2304 * 2 + (size_t)8192 * 768 * 2);
  u16* wqkvb  = xb + NX;
  u16* wprojb = wqkvb + NQ;

  int cvt_blocks = ((NX + NQ + NP) / 4 + 255) / 256;
  cvt_bf16<<<dim3(cvt_blocks), 256, 0, stream>>>(x, xb, NX, Wqkv, wqkvb, NQ, Wproj, wprojb, NP);

  gemm_bt<768, 128, 2304, true><<<dim3(18, 64), 256, 0, stream>>>(xb, wqkvb, qkv, nullptr);
  attn_mfma<<<dim3(768), 256, 0, stream>>>(qkv, mask, ctx);
  gemm_bt<768, 64, 768, false><<<dim3(12, 64), 256, 0, stream>>>(ctx, wprojb, out, bproj);
}

// Round 5
// 191.491 us; speedup vs baseline: 1.0783x; 1.0571x over previous
//
#include <hip/hip_runtime.h>
#include <hip/hip_bf16.h>
#include <stdint.h>

// B=8, N=1024, D=768, H=12, hd=64
// cvt(x,Wqkv,Wproj -> bf16 ws) -> MFMA gemm qkv -> MFMA flash attention -> MFMA gemm proj + bias

typedef unsigned short u16;
typedef __attribute__((ext_vector_type(8))) short short8;
typedef __attribute__((ext_vector_type(4))) float f32x4;

#define MFMA16(a, b, c) __builtin_amdgcn_mfma_f32_16x16x32_bf16((a), (b), (c), 0, 0, 0)

static __device__ __forceinline__ u16 f2bf(float f) {
    __hip_bfloat16 h = __float2bfloat16(f);
    return *(u16*)&h;
}
// async global->LDS, 16B per lane; LDS dest must be wave-uniform base + lane*16
static __device__ __forceinline__ void gld16(const u16* g, u16* l) {
  __builtin_amdgcn_global_load_lds(
      (const __attribute__((address_space(1))) void*)g,
      (__attribute__((address_space(3))) void*)l, 16, 0, 0);
}

// ---------------- fp32 -> bf16 conversion of the three input tensors
__global__ __launch_bounds__(256) void cvt_bf16(
    const float* __restrict__ s0, u16* __restrict__ d0, int n0,
    const float* __restrict__ s1, u16* __restrict__ d1, int n1,
    const float* __restrict__ s2, u16* __restrict__ d2, int n2) {
  int i = (blockIdx.x * 256 + threadIdx.x) * 4;
  const float* s; u16* d;
  if (i < n0) { s = s0 + i; d = d0 + i; }
  else if ((i -= n0) < n1) { s = s1 + i; d = d1 + i; }
  else if ((i -= n1) < n2) { s = s2 + i; d = d2 + i; }
  else return;
  float4 v = *(const float4*)s;
  ushort4 o;
  o.x = f2bf(v.x); o.y = f2bf(v.y); o.z = f2bf(v.z); o.w = f2bf(v.w);
  *(ushort4*)d = o;
}

// ---------------- MFMA GEMM: C[M][LDC] = A[M][K](bf16) * B[N][K](bf16)^T
// Round 5: reverted to the round-2 BK=32 2-barrier m97 structure (dbuf and
// BK=64 both regressed) + T1 chunked XCD swizzle. Round-4 counters showed
// FETCH_SIZE 70.5 MB vs ~16 MB ideal: the 18 column-tiles sharing one
// 128-row A-slab were round-robined across all 8 XCDs, so each slab was
// fetched up to 8x through different private L2s at fabric latency — naked
// latency in this serial stage->drain->compute loop. Chunked swizzle
// (bijective, nwg%8==0): XCD k owns contiguous logical tiles; one A-slab's
// column-tiles run back-to-back in one L2.
// NXB = tiles in x (columns); grid is 1D nwg = NXB*64.
template<int K, int BN, int LDC, bool BF16OUT, int NXB>
__global__ __launch_bounds__(256) void gemm_bt(
    const u16* __restrict__ A,
    const u16* __restrict__ B,
    void* __restrict__ Cout,
    const float* __restrict__ bias) {
  constexpr int NT = BN / 32;          // n-tiles per wave
  __shared__ u16 As[128 * 32];
  __shared__ u16 Bs[BN * 32];
  const int tid = threadIdx.x;
  const int w = tid >> 6, l = tid & 63;
  const int lane16 = l & 15, quad = l >> 4;

  // T1: orig%8 is this block's XCD (round-robin dispatch); give XCD k the
  // contiguous logical range [k*q, (k+1)*q). x fastest within logical space.
  constexpr int nwg = NXB * 64;
  constexpr int qch = nwg / 8;         // nwg % 8 == 0 for both instantiations
  const int orig = blockIdx.x;
  const int logical = (orig & 7) * qch + (orig >> 3);
  const int i0 = (logical / NXB) * 128, j0 = (logical % NXB) * BN;

  const int mh = (w & 1) * 64;
  const int nh = (w >> 1) * (BN / 2);

  f32x4 acc[4][NT];
  #pragma unroll
  for (int mt = 0; mt < 4; mt++)
    #pragma unroll
    for (int nt = 0; nt < NT; nt++) acc[mt][nt] = (f32x4){0.f, 0.f, 0.f, 0.f};

  for (int kt = 0; kt < K / 32; kt++) {
    const int k0 = kt * 32;
    __syncthreads();
    #pragma unroll
    for (int s = 0; s < 2; s++) {            // A: 128x32 bf16 -> 2 gld16/thread
      int idx = tid + s * 256;
      int row = idx >> 2, c8 = (idx & 3) * 8;
      gld16(&A[(size_t)(i0 + row) * K + k0 + c8], &As[idx * 8]);
    }
    #pragma unroll
    for (int s = 0; s < BN / 64; s++) {      // B: BNx32 bf16
      int idx = tid + s * 256;
      int row = idx >> 2, c8 = (idx & 3) * 8;
      gld16(&B[(size_t)(j0 + row) * K + k0 + c8], &Bs[idx * 8]);
    }
    __syncthreads();

    short8 af[4], bf[NT];
    #pragma unroll
    for (int mt = 0; mt < 4; mt++)
      af[mt] = *(const short8*)&As[(mh + mt * 16 + lane16) * 32 + quad * 8];
    #pragma unroll
    for (int nt = 0; nt < NT; nt++)
      bf[nt] = *(const short8*)&Bs[(nh + nt * 16 + lane16) * 32 + quad * 8];
    #pragma unroll
    for (int mt = 0; mt < 4; mt++)
      #pragma unroll
      for (int nt = 0; nt < NT; nt++)
        acc[mt][nt] = MFMA16(af[mt], bf[nt], acc[mt][nt]);
  }

  #pragma unroll
  for (int mt = 0; mt < 4; mt++) {
    #pragma unroll
    for (int nt = 0; nt < NT; nt++) {
      int col = j0 + nh + nt * 16 + lane16;
      #pragma unroll
      for (int r = 0; r < 4; r++) {
        int row = i0 + mh + mt * 16 + quad * 4 + r;
        if (BF16OUT) {
          ((u16*)Cout)[(size_t)row * LDC + col] = f2bf(acc[mt][nt][r]);
        } else {
          ((float*)Cout)[(size_t)row * LDC + col] = acc[mt][nt][r] + bias[col];
        }
      }
    }
  }
}

// ---------------- Attention: MFMA flash, transposed-S, fixed-max softmax.
// r6 structure + T14 async-STAGE + setprio + f32x4 lsum (round 2, verified)
// + mkb_all one-time mask table (round 3). LDS 40 KB, 3 blocks/CU (= grid).
// XCD swizzle: idx = rb*96 + bh so all 8 row-blocks of one (b,h) share an XCD L2.
// Block = 4 waves, 128 q-rows, grid 768.
__global__ __launch_bounds__(256, 3) void attn_mfma(
    const u16* __restrict__ qkv,   // bf16 bits, [B*N][2304]; q +0, k +768, v +1536 (+h*64)
    const int* __restrict__ mask,
    u16* __restrict__ ctx) {
  __shared__ u16 Ks[64][72];      // [key][dim]
  __shared__ u16 Vt[64][72];      // [dim][key]
  __shared__ u16 Ps[4][32][72];   // per-wave P [qrow_local][key]
  __shared__ float mkb_all[1024]; // 0 or -1e38 additive key-mask bias, whole seq

  const int tid = threadIdx.x;
  const int w = tid >> 6, l = tid & 63;
  const int lane16 = l & 15, quad = l >> 4;
  const int idx = blockIdx.x;
  const int bh = idx % 96;        // 96 % 8 == 0 -> same bh => same XCD
  const int rb = idx / 96;
  const int b = bh / 12, h = bh % 12;
  const int n0 = rb * 128;
  const int baseRow = b * 1024;

  // staging thread mapping
  const int key_s = tid >> 2, ds_s = (tid & 3) * 16;      // K: 1 key, 32 dims
  const int kA_s = (tid & 31) * 2, dg_s = tid >> 5;       // V: 2 keys, 8 dims

  // whole-sequence mask bias table (written once; first compute barrier covers it)
  {
    int4 mv = *(const int4*)&mask[baseRow + tid * 4];
    f32x4 mf;
    mf[0] = mv.x ? 0.f : -1e38f;
    mf[1] = mv.y ? 0.f : -1e38f;
    mf[2] = mv.z ? 0.f : -1e38f;
    mf[3] = mv.w ? 0.f : -1e38f;
    *(f32x4*)&mkb_all[tid * 4] = mf;
  }

  // Q fragments (used as MFMA B operand): n=lane16 (local qrow), k=quad*8+j
  short8 qfrag[2][2];
  #pragma unroll
  for (int qt = 0; qt < 2; qt++) {
    const u16* qp = qkv + (size_t)(baseRow + n0 + w*32 + qt*16 + lane16) * 2304 + h*64;
    #pragma unroll
    for (int ks = 0; ks < 2; ks++)
      qfrag[qt][ks] = *(const short8*)(qp + ks*32 + quad*8);
  }

  f32x4 oacc[2][4];     // [qt][nt(dim)]; C-layout row=quad*4+r=qrow, col=lane16=dim
  #pragma unroll
  for (int qt = 0; qt < 2; qt++)
    #pragma unroll
    for (int nt = 0; nt < 4; nt++) oacc[qt][nt] = (f32x4){0.f, 0.f, 0.f, 0.f};
  f32x4 lsum4[2] = {(f32x4){0.f,0.f,0.f,0.f}, (f32x4){0.f,0.f,0.f,0.f}};

  // exp(s/8 - 16) == exp2(s*K1 + K0); fixed max >> max score (~8 sigma), overflow-free.
  const float K1 = 0.18033688011112043f;   // log2(e)/8
  const float K0 = -23.083120654223415f;   // -16*log2(e)

  // ---- T14 prologue: issue chunk-0 K/V loads into registers
  uint4 kr0, kr1, vr0, vr1;
  {
    const u16* kp = qkv + (size_t)(baseRow + key_s) * 2304 + 768 + h*64 + ds_s;
    kr0 = *(const uint4*)kp;
    kr1 = *(const uint4*)(kp + 8);
    const u16* vp = qkv + (size_t)(baseRow + kA_s) * 2304 + 1536 + h*64 + dg_s*8;
    vr0 = *(const uint4*)vp;
    vr1 = *(const uint4*)(vp + 2304);
  }

  for (int c = 0; c < 16; c++) {
    if (c) __syncthreads();   // prior chunk's LDS reads complete before overwrite

    // ---- write staged registers (chunk c) into LDS
    *(uint4*)&Ks[key_s][ds_s]     = kr0;
    *(uint4*)&Ks[key_s][ds_s + 8] = kr1;
    {
      const u16* va = (const u16*)&vr0;
      const u16* vb = (const u16*)&vr1;
      #pragma unroll
      for (int j = 0; j < 8; j++)
        *(unsigned int*)&Vt[dg_s*8 + j][kA_s] =
            (unsigned int)va[j] | ((unsigned int)vb[j] << 16);
    }

    // ---- issue chunk c+1's global loads (registers only; latency hides
    //      under this chunk's MFMA + softmax)
    if (c + 1 < 16) {
      const u16* kp = qkv + (size_t)(baseRow + (c+1)*64 + key_s) * 2304 + 768 + h*64 + ds_s;
      kr0 = *(const uint4*)kp;
      kr1 = *(const uint4*)(kp + 8);
      const u16* vp = qkv + (size_t)(baseRow + (c+1)*64 + kA_s) * 2304 + 1536 + h*64 + dg_s*8;
      vr0 = *(const uint4*)vp;
      vr1 = *(const uint4*)(vp + 2304);
    }
    __syncthreads();          // chunk c visible to all waves

    // S^T = K * Q^T : A=K (m=key), B=Q (n=qrow). C-layout: row=key, col=qrow.
    f32x4 sacc[4][2];
    #pragma unroll
    for (int kt = 0; kt < 4; kt++)
      #pragma unroll
      for (int qt = 0; qt < 2; qt++) sacc[kt][qt] = (f32x4){0.f, 0.f, 0.f, 0.f};
    #pragma unroll
    for (int ks = 0; ks < 2; ks++) {
      short8 kf[4];
      #pragma unroll
      for (int kt = 0; kt < 4; kt++)
        kf[kt] = *(const short8*)&Ks[kt*16 + lane16][ks*32 + quad*8];
      __builtin_amdgcn_s_setprio(1);
      #pragma unroll
      for (int kt = 0; kt < 4; kt++)
        #pragma unroll
        for (int qt = 0; qt < 2; qt++)
          sacc[kt][qt] = MFMA16(kf[kt], qfrag[qt][ks], sacc[kt][qt]);
      __builtin_amdgcn_s_setprio(0);
    }

    // softmax: row=quad*4+r = key-local, col=lane16 = qrow-local. Vectorized P write.
    #pragma unroll
    for (int kt = 0; kt < 4; kt++) {
      f32x4 mk4 = *(const f32x4*)&mkb_all[c*64 + kt*16 + quad*4];   // contiguous keys
      #pragma unroll
      for (int qt = 0; qt < 2; qt++) {
        u16 pk[4];
        #pragma unroll
        for (int r = 0; r < 4; r++) {
          float e = __builtin_amdgcn_exp2f(fmaf(sacc[kt][qt][r], K1, K0) + mk4[r]);
          lsum4[qt][r] += e;
          pk[r] = f2bf(e);
        }
        uint2 pv;
        pv.x = (unsigned int)pk[0] | ((unsigned int)pk[1] << 16);
        pv.y = (unsigned int)pk[2] | ((unsigned int)pk[3] << 16);
        *(uint2*)&Ps[w][qt*16 + lane16][kt*16 + quad*4] = pv;
      }
    }

    // O += P * V : A=P (m=qrow, k=key) own-wave LDS; B=V^T (n=dim, k=key) from Vt.
    #pragma unroll
    for (int kc = 0; kc < 2; kc++) {
      short8 pf[2], vf[4];
      #pragma unroll
      for (int qt = 0; qt < 2; qt++)
        pf[qt] = *(const short8*)&Ps[w][qt*16 + lane16][kc*32 + quad*8];
      #pragma unroll
      for (int nt = 0; nt < 4; nt++)
        vf[nt] = *(const short8*)&Vt[nt*16 + lane16][kc*32 + quad*8];
      __builtin_amdgcn_s_setprio(1);
      #pragma unroll
      for (int qt = 0; qt < 2; qt++)
        #pragma unroll
        for (int nt = 0; nt < 4; nt++)
          oacc[qt][nt] = MFMA16(pf[qt], vf[nt], oacc[qt][nt]);
      __builtin_amdgcn_s_setprio(0);
    }
  }

  // lsum: reduce across quads, then redistribute to the C-layout row owner.
  float linv[2][4];
  #pragma unroll
  for (int qt = 0; qt < 2; qt++) {
    float s = lsum4[qt][0] + lsum4[qt][1] + lsum4[qt][2] + lsum4[qt][3];
    s += __shfl_xor(s, 16);
    s += __shfl_xor(s, 32);   // every lane: total for qrow = its lane16 (tile qt)
    #pragma unroll
    for (int r = 0; r < 4; r++)
      linv[qt][r] = 1.0f / __shfl(s, quad*4 + r);
  }
  // store; masked query rows get exactly their own V row (bit-exact copy)
  #pragma unroll
  for (int qt = 0; qt < 2; qt++) {
    #pragma unroll
    for (int r = 0; r < 4; r++) {
      int rl = w*32 + qt*16 + quad*4 + r;
      int rg = n0 + rl;
      int mq = (mkb_all[n0 + rl] == 0.f);
      #pragma unroll
      for (int nt = 0; nt < 4; nt++) {
        u16 outv;
        if (mq) {
          outv = f2bf(oacc[qt][nt][r] * linv[qt][r]);
        } else {
          outv = qkv[(size_t)(baseRow + rg) * 2304 + 1536 + h*64 + nt*16 + lane16];
        }
        ctx[(size_t)(baseRow + rg) * 768 + h*64 + nt*16 + lane16] = outv;
      }
    }
  }
}

extern "C" void kernel_launch(void* const* d_in, const int* in_sizes, int n_in,
                              void* d_out, int out_size, void* d_ws, size_t ws_size,
                              hipStream_t stream) {
  const float* x     = (const float*)d_in[0];
  const int*   mask  = (const int*)d_in[1];
  const float* Wqkv  = (const float*)d_in[2];
  const float* Wproj = (const float*)d_in[3];
  const float* bproj = (const float*)d_in[4];
  float* out = (float*)d_out;

  const int NX = 8192 * 768;
  const int NQ = 2304 * 768;
  const int NP = 768 * 768;

  char* wsb = (char*)d_ws;
  u16* qkv    = (u16*)wsb;                                  // 37.75 MB
  u16* ctx    = (u16*)(wsb + (size_t)8192 * 2304 * 2);      // 12.58 MB
  u16* xb     = (u16*)(wsb + (size_t)8192 * 2304 * 2 + (size_t)8192 * 768 * 2);
  u16* wqkvb  = xb + NX;
  u16* wprojb = wqkvb + NQ;

  int cvt_blocks = ((NX + NQ + NP) / 4 + 255) / 256;
  cvt_bf16<<<dim3(cvt_blocks), 256, 0, stream>>>(x, xb, NX, Wqkv, wqkvb, NQ, Wproj, wprojb, NP);

  gemm_bt<768, 128, 2304, true, 18><<<dim3(18 * 64), 256, 0, stream>>>(xb, wqkvb, qkv, nullptr);
  attn_mfma<<<dim3(768), 256, 0, stream>>>(qkv, mask, ctx);
  gemm_bt<768, 64, 768, false, 12><<<dim3(12 * 64), 256, 0, stream>>>(ctx, wprojb, out, bproj);
}